// Round 3
// baseline (314.406 us; speedup 1.0000x reference)
//
#include <hip/hip_runtime.h>
#include <stdint.h>

#define T_LEN 4096
#define C_DIM 1024
#define NH 16
#define LSTR 72
#define CLOG2E 0.18033688011112042f   // 0.125 * log2(e)

typedef uint16_t u16;
typedef __attribute__((ext_vector_type(4))) float f32x4;
typedef __attribute__((ext_vector_type(8))) __bf16 bf16x8;
typedef __attribute__((ext_vector_type(8))) uint16_t u16x8;
typedef __attribute__((ext_vector_type(4))) uint16_t u16x4;
typedef __attribute__((ext_vector_type(4))) float fvec4;

static __device__ __forceinline__ u16 f2b(float f) {
  union { float f; uint32_t u; } v; v.f = f;
  uint32_t u = v.u;
  return (u16)((u + 0x7fffu + ((u >> 16) & 1u)) >> 16);
}

// packed fp32->bf16x2 (RNE) — no builtin on gfx950, inline asm (T12 primitive)
static __device__ __forceinline__ uint32_t cvtpk(float lo, float hi) {
  uint32_t r;
  asm("v_cvt_pk_bf16_f32 %0, %1, %2" : "=v"(r) : "v"(lo), "v"(hi));
  return r;
}

static __device__ __forceinline__ f32x4 mfma16(u16x8 a, u16x8 b, f32x4 c) {
  return __builtin_amdgcn_mfma_f32_16x16x32_bf16(
      __builtin_bit_cast(bf16x8, a), __builtin_bit_cast(bf16x8, b), c, 0, 0, 0);
}

static __device__ __forceinline__ void gload_lds16(const void* g, void* l) {
  __builtin_amdgcn_global_load_lds(
      (const __attribute__((address_space(1))) uint32_t*)g,
      (__attribute__((address_space(3))) uint32_t*)l, 16, 0, 0);
}

// ---------------- fp32 -> bf16 cast (vectorized) ----------------
__global__ void cvt_kernel(const float* __restrict__ in, u16* __restrict__ out, int n8) {
  int i = blockIdx.x * blockDim.x + threadIdx.x;
  if (i >= n8) return;
  const fvec4* p = (const fvec4*)(in + (size_t)i * 8);
  fvec4 a = p[0], b = p[1];
  u16x8 o;
  o[0] = f2b(a[0]); o[1] = f2b(a[1]); o[2] = f2b(a[2]); o[3] = f2b(a[3]);
  o[4] = f2b(b[0]); o[5] = f2b(b[1]); o[6] = f2b(b[2]); o[7] = f2b(b[3]);
  *(u16x8*)(out + (size_t)i * 8) = o;
}

__global__ void wcvt_kernel(const float* __restrict__ w0, const float* __restrict__ w1,
                            const float* __restrict__ w2, const float* __restrict__ w3,
                            u16* __restrict__ o0, u16* __restrict__ o1,
                            u16* __restrict__ o2, u16* __restrict__ o3, int n8) {
  int i = blockIdx.x * blockDim.x + threadIdx.x;
  if (i >= n8) return;
  const int z = blockIdx.y;
  const float* in = (z == 0) ? w0 : (z == 1) ? w1 : (z == 2) ? w2 : w3;
  u16* out = (z == 0) ? o0 : (z == 1) ? o1 : (z == 2) ? o2 : o3;
  const fvec4* p = (const fvec4*)(in + (size_t)i * 8);
  fvec4 a = p[0], b = p[1];
  u16x8 o;
  o[0] = f2b(a[0]); o[1] = f2b(a[1]); o[2] = f2b(a[2]); o[3] = f2b(a[3]);
  o[4] = f2b(b[0]); o[5] = f2b(b[1]); o[6] = f2b(b[2]); o[7] = f2b(b[3]);
  *(u16x8*)(out + (size_t)i * 8) = o;
}

// ---------------- QKV GEMM (m97 structure) ----------------
// z=0: Q head-major, PRE-SCALED by 0.125*log2e (fp32, exact). z=1: K. z=2: V^T [h][d][t].
__global__ __launch_bounds__(256) void gemm_qkv(
    const u16* __restrict__ xb,
    const u16* __restrict__ wqb, const u16* __restrict__ wkb, const u16* __restrict__ wvb,
    const float* __restrict__ bq, const float* __restrict__ bk, const float* __restrict__ bv,
    u16* __restrict__ qh, u16* __restrict__ kh, u16* __restrict__ vt)
{
  __shared__ u16 sA[128 * 32];
  __shared__ u16 sB[128 * 32];
  const int K = C_DIM;
  const int z = blockIdx.z;
  const u16* wb = (z == 0) ? wqb : (z == 1) ? wkb : wvb;
  const float* bias = (z == 0) ? bq : (z == 1) ? bk : bv;
  const int m0 = blockIdx.x * 128;
  const int n0 = blockIdx.y * 128;
  const int tid = threadIdx.x;
  const int lane = tid & 63;
  const int w = tid >> 6;
  const int wm = (w >> 1) * 64;
  const int wn = (w & 1) * 64;
  const int lr = lane & 15;
  const int lk = (lane >> 4) * 8;

  f32x4 acc[4][4];
#pragma unroll
  for (int m = 0; m < 4; ++m)
#pragma unroll
    for (int n = 0; n < 4; ++n) acc[m][n] = (f32x4){0.f, 0.f, 0.f, 0.f};

  const int srow = tid >> 2;
  const int scol = (tid & 3) * 8;
  const u16* gA = xb + (size_t)(m0 + srow) * K + scol;
  const u16* gB = wb + (size_t)(n0 + srow) * K + scol;

  for (int k0 = 0; k0 < K; k0 += 32) {
    gload_lds16(gA + k0,          &sA[tid * 8]);
    gload_lds16(gA + 64 * K + k0, &sA[2048 + tid * 8]);
    gload_lds16(gB + k0,          &sB[tid * 8]);
    gload_lds16(gB + 64 * K + k0, &sB[2048 + tid * 8]);
    __syncthreads();
    u16x8 af[4], bfr[4];
#pragma unroll
    for (int m = 0; m < 4; ++m) af[m]  = *(const u16x8*)&sA[(wm + m * 16 + lr) * 32 + lk];
#pragma unroll
    for (int n = 0; n < 4; ++n) bfr[n] = *(const u16x8*)&sB[(wn + n * 16 + lr) * 32 + lk];
#pragma unroll
    for (int m = 0; m < 4; ++m)
#pragma unroll
      for (int n = 0; n < 4; ++n) acc[m][n] = mfma16(af[m], bfr[n], acc[m][n]);
    __syncthreads();
  }

  const int lg = lane >> 4;
#pragma unroll
  for (int n = 0; n < 4; ++n) {
    const int o = n0 + wn + n * 16 + lr;
    const float bb = bias[o];
    const int h = o >> 6;
    const int d = o & 63;
#pragma unroll
    for (int m = 0; m < 4; ++m) {
      const int tb = m0 + wm + m * 16 + lg * 4;
      if (z == 2) {
        uint2 pk;
        pk.x = cvtpk(acc[m][n][0] + bb, acc[m][n][1] + bb);
        pk.y = cvtpk(acc[m][n][2] + bb, acc[m][n][3] + bb);
        *(uint2*)&vt[(size_t)o * T_LEN + tb] = pk;
      } else if (z == 0) {
#pragma unroll
        for (int r = 0; r < 4; ++r)
          qh[((size_t)h * T_LEN + tb + r) * 64 + d] = f2b((acc[m][n][r] + bb) * CLOG2E);
      } else {
#pragma unroll
        for (int r = 0; r < 4; ++r)
          kh[((size_t)h * T_LEN + tb + r) * 64 + d] = f2b(acc[m][n][r] + bb);
      }
    }
  }
}

// ---------------- output projection ----------------
__global__ __launch_bounds__(256) void gemm_proj(
    const u16* __restrict__ yb, const u16* __restrict__ wpb,
    const float* __restrict__ bp, float* __restrict__ out)
{
  __shared__ u16 sA[128 * 32];
  __shared__ u16 sB[128 * 32];
  const int K = C_DIM;
  const int m0 = blockIdx.x * 128;
  const int n0 = blockIdx.y * 128;
  const int tid = threadIdx.x;
  const int lane = tid & 63;
  const int w = tid >> 6;
  const int wm = (w >> 1) * 64;
  const int wn = (w & 1) * 64;
  const int lr = lane & 15;
  const int lk = (lane >> 4) * 8;

  f32x4 acc[4][4];
#pragma unroll
  for (int m = 0; m < 4; ++m)
#pragma unroll
    for (int n = 0; n < 4; ++n) acc[m][n] = (f32x4){0.f, 0.f, 0.f, 0.f};

  const int srow = tid >> 2;
  const int scol = (tid & 3) * 8;
  const u16* gA = yb  + (size_t)(m0 + srow) * K + scol;
  const u16* gB = wpb + (size_t)(n0 + srow) * K + scol;

  for (int k0 = 0; k0 < K; k0 += 32) {
    gload_lds16(gA + k0,          &sA[tid * 8]);
    gload_lds16(gA + 64 * K + k0, &sA[2048 + tid * 8]);
    gload_lds16(gB + k0,          &sB[tid * 8]);
    gload_lds16(gB + 64 * K + k0, &sB[2048 + tid * 8]);
    __syncthreads();
    u16x8 af[4], bfr[4];
#pragma unroll
    for (int m = 0; m < 4; ++m) af[m]  = *(const u16x8*)&sA[(wm + m * 16 + lr) * 32 + lk];
#pragma unroll
    for (int n = 0; n < 4; ++n) bfr[n] = *(const u16x8*)&sB[(wn + n * 16 + lr) * 32 + lk];
#pragma unroll
    for (int m = 0; m < 4; ++m)
#pragma unroll
      for (int n = 0; n < 4; ++n) acc[m][n] = mfma16(af[m], bfr[n], acc[m][n]);
    __syncthreads();
  }

  const int lg = lane >> 4;
#pragma unroll
  for (int n = 0; n < 4; ++n) {
    const int o = n0 + wn + n * 16 + lr;
    const float bb = bp[o];
#pragma unroll
    for (int m = 0; m < 4; ++m) {
      const int tb = m0 + wm + m * 16 + lg * 4;
#pragma unroll
      for (int r = 0; r < 4; ++r)
        out[(size_t)(tb + r) * C_DIM + o] = acc[m][n][r] + bb;
    }
  }
}

// ---------------- flash attention v3 ----------------
// Grid (64, 16) free-running blocks, longest-first (qb = 63-bx). 256 thr = 4 waves.
// K LDS-staged (XOR swizzle, double-buffered, 1 barrier/tile); V fragments read
// DIRECT from global (L2-resident; m169). Q pre-scaled. cvt_pk for all bf16 packs.
__global__ __launch_bounds__(256) void attn_kernel(
    const u16* __restrict__ qh, const u16* __restrict__ kh, const u16* __restrict__ vt,
    u16* __restrict__ y)
{
  __shared__ char skb[2][8192];
  __shared__ u16 pp[4][16][LSTR];
  const int h = blockIdx.y;
  const int qb = 63 - blockIdx.x;       // longest-first dispatch
  const int nt = qb + 1;
  const int tid = threadIdx.x;
  const int lane = tid & 63;
  const int w = tid >> 6;
  const int lr = lane & 15;
  const int lg = lane >> 4;
  const int sw = (lr & 7) << 4;
  const int qt0 = qb * 64 + w * 16;

  // Q fragments (already scaled by 0.125*log2e)
  const u16* qbase = qh + ((size_t)h * T_LEN + qt0 + lr) * 64 + lg * 8;
  u16x8 qf0 = *(const u16x8*)(qbase);
  u16x8 qf1 = *(const u16x8*)(qbase + 32);

  // K staging (64x64 tile = 8KB, XOR-swizzled rows of 128B)
  const int srow = tid >> 2;
  const int scb = (tid & 3) * 32;
  const int wo0 = srow * 128 + (scb ^ ((srow & 7) << 4));
  const int wo1 = srow * 128 + ((scb + 16) ^ ((srow & 7) << 4));
  const u16* gkbase = kh + ((size_t)h * T_LEN + srow) * 64 + (tid & 3) * 16;
  // V direct-from-global fragment base: row d = dblk*16 + lr, k-chunk at lg*8
  const u16* gvf = vt + ((size_t)h * 64 + lr) * T_LEN + lg * 8;
  u16* ppw = &pp[w][0][0];

  f32x4 oacc[4];
#pragma unroll
  for (int i = 0; i < 4; ++i) oacc[i] = (f32x4){0.f, 0.f, 0.f, 0.f};
  float mrow = -1e30f, lsum = 0.f;

  // prologue: stage K tile 0
  u16x8 ka = *(const u16x8*)(gkbase);
  u16x8 kb = *(const u16x8*)(gkbase + 8);
  *(u16x8*)(skb[0] + wo0) = ka; *(u16x8*)(skb[0] + wo1) = kb;
  int cur = 0;

  for (int t = 0; t < nt; ++t) {
    const int kt0 = t * 64;
    if (t + 1 < nt) {   // reg-stage next K tile (T14: issue early)
      const size_t ko = (size_t)(t + 1) * 4096;
      ka = *(const u16x8*)(gkbase + ko);
      kb = *(const u16x8*)(gkbase + ko + 8);
    }
    __syncthreads();
    const char* skc = skb[cur];

    // S^T = K * Q^T
    f32x4 sacc[4];
#pragma unroll
    for (int i = 0; i < 4; ++i) {
      const int ro = (i * 16 + lr) * 128;
      u16x8 a0 = *(const u16x8*)(skc + ro + ((lg * 16) ^ sw));
      u16x8 a1 = *(const u16x8*)(skc + ro + ((lg * 16 + 64) ^ sw));
      f32x4 zz = (f32x4){0.f, 0.f, 0.f, 0.f};
      zz = mfma16(a0, qf0, zz);
      zz = mfma16(a1, qf1, zz);
      sacc[i] = zz;
    }

    // issue V fragment loads early (hide L2 latency under softmax)
    u16x8 vfr0[4], vfr1[4];
#pragma unroll
    for (int dblk = 0; dblk < 4; ++dblk) {
      const u16* vb = gvf + (size_t)dblk * 16 * T_LEN + kt0;
      vfr0[dblk] = *(const u16x8*)(vb);
      vfr1[dblk] = *(const u16x8*)(vb + 32);
    }

    // softmax (S already has scale folded in via Q)
    float pvv[4][4];
    float pm = -1e30f;
    if (t == nt - 1) {               // diagonal tile: causal mask
      const int qg = qt0 + lr;
#pragma unroll
      for (int i = 0; i < 4; ++i) {
#pragma unroll
        for (int r = 0; r < 4; ++r) {
          const int kt = kt0 + i * 16 + lg * 4 + r;
          pvv[i][r] = (kt <= qg) ? sacc[i][r] : -1e30f;
        }
        pm = fmaxf(pm, fmaxf(fmaxf(pvv[i][0], pvv[i][1]), fmaxf(pvv[i][2], pvv[i][3])));
      }
    } else {
#pragma unroll
      for (int i = 0; i < 4; ++i) {
#pragma unroll
        for (int r = 0; r < 4; ++r) pvv[i][r] = sacc[i][r];
        pm = fmaxf(pm, fmaxf(fmaxf(pvv[i][0], pvv[i][1]), fmaxf(pvv[i][2], pvv[i][3])));
      }
    }
    pm = fmaxf(pm, __shfl_xor(pm, 16));
    pm = fmaxf(pm, __shfl_xor(pm, 32));

    if (!__all(pm <= mrow)) {        // defer-max (T13)
      const float mnew = fmaxf(mrow, pm);
      const float sc = exp2f(mrow - mnew);
      lsum *= sc;
#pragma unroll
      for (int i = 0; i < 4; ++i) oacc[i] *= sc;
      mrow = mnew;
    }

    float tsum = 0.f;
#pragma unroll
    for (int i = 0; i < 4; ++i) {
      float e0 = exp2f(pvv[i][0] - mrow);
      float e1 = exp2f(pvv[i][1] - mrow);
      float e2 = exp2f(pvv[i][2] - mrow);
      float e3 = exp2f(pvv[i][3] - mrow);
      tsum += (e0 + e1) + (e2 + e3);
      uint2 pk;
      pk.x = cvtpk(e0, e1);
      pk.y = cvtpk(e2, e3);
      *(uint2*)&ppw[lr * LSTR + i * 16 + lg * 4] = pk;
    }
    tsum += __shfl_xor(tsum, 16);
    tsum += __shfl_xor(tsum, 32);
    lsum += tsum;

    // O^T += V^T * P^T  (V fragments from regs, P via wave-private LDS)
#pragma unroll
    for (int ks = 0; ks < 2; ++ks) {
      u16x8 pf = *(const u16x8*)&ppw[lr * LSTR + lg * 8 + ks * 32];
#pragma unroll
      for (int dblk = 0; dblk < 4; ++dblk)
        oacc[dblk] = mfma16(ks ? vfr1[dblk] : vfr0[dblk], pf, oacc[dblk]);
    }

    if (t + 1 < nt) {
      char* dk = skb[cur ^ 1];
      *(u16x8*)(dk + wo0) = ka; *(u16x8*)(dk + wo1) = kb;
    }
    cur ^= 1;
  }

  const float inv = 1.0f / lsum;
#pragma unroll
  for (int dblk = 0; dblk < 4; ++dblk) {
    uint2 pk;
    pk.x = cvtpk(oacc[dblk][0] * inv, oacc[dblk][1] * inv);
    pk.y = cvtpk(oacc[dblk][2] * inv, oacc[dblk][3] * inv);
    *(uint2*)&y[(size_t)(qt0 + lr) * C_DIM + h * 64 + dblk * 16 + lg * 4] = pk;
  }
}

extern "C" void kernel_launch(void* const* d_in, const int* in_sizes, int n_in,
                              void* d_out, int out_size, void* d_ws, size_t ws_size,
                              hipStream_t stream) {
  const float* x  = (const float*)d_in[0];
  const float* wq = (const float*)d_in[1];
  const float* bq = (const float*)d_in[2];
  const float* wk = (const float*)d_in[3];
  const float* bk = (const float*)d_in[4];
  const float* wv = (const float*)d_in[5];
  const float* bv = (const float*)d_in[6];
  const float* wp = (const float*)d_in[7];
  const float* bp = (const float*)d_in[8];

  char* ws = (char*)d_ws;
  const size_t MB = 1024 * 1024;
  u16* xb  = (u16*)(ws + 0 * MB);
  u16* wqb = (u16*)(ws + 8 * MB);
  u16* wkb = (u16*)(ws + 10 * MB);
  u16* wvb = (u16*)(ws + 12 * MB);
  u16* wpb = (u16*)(ws + 14 * MB);
  u16* qh  = (u16*)(ws + 16 * MB);
  u16* kh  = (u16*)(ws + 24 * MB);
  u16* vt  = (u16*)(ws + 32 * MB);
  u16* y   = (u16*)(ws + 40 * MB);

  cvt_kernel<<<dim3(2048), dim3(256), 0, stream>>>(x, xb, 524288);
  wcvt_kernel<<<dim3(512, 4), dim3(256), 0, stream>>>(
      wq, wk, wv, wp, wqb, wkb, wvb, wpb, 131072);

  gemm_qkv<<<dim3(32, 8, 3), dim3(256), 0, stream>>>(
      xb, wqb, wkb, wvb, bq, bk, bv, qh, kh, vt);

  attn_kernel<<<dim3(64, 16), dim3(256), 0, stream>>>(qh, kh, vt, y);

  gemm_proj<<<dim3(32, 8), dim3(256), 0, stream>>>(y, wpb, bp, (float*)d_out);
}

// Round 4
// 156.646 us; speedup vs baseline: 2.0071x; 2.0071x over previous
//
#include <hip/hip_runtime.h>
#include <stdint.h>

#define T_LEN 4096
#define C_DIM 1024
#define NH 16
#define LSTR 72
#define CLOG2E 0.18033688011112042f   // 0.125 * log2(e)

typedef uint16_t u16;
typedef __attribute__((ext_vector_type(4))) float f32x4;
typedef __attribute__((ext_vector_type(8))) __bf16 bf16x8;
typedef __attribute__((ext_vector_type(8))) uint16_t u16x8;
typedef __attribute__((ext_vector_type(4))) uint16_t u16x4;
typedef __attribute__((ext_vector_type(4))) float fvec4;

static __device__ __forceinline__ u16 f2b(float f) {
  union { float f; uint32_t u; } v; v.f = f;
  uint32_t u = v.u;
  return (u16)((u + 0x7fffu + ((u >> 16) & 1u)) >> 16);
}

// packed fp32->bf16x2 (RNE) — inline asm, no builtin on gfx950
static __device__ __forceinline__ uint32_t cvtpk(float lo, float hi) {
  uint32_t r;
  asm("v_cvt_pk_bf16_f32 %0, %1, %2" : "=v"(r) : "v"(lo), "v"(hi));
  return r;
}

static __device__ __forceinline__ f32x4 mfma16(u16x8 a, u16x8 b, f32x4 c) {
  return __builtin_amdgcn_mfma_f32_16x16x32_bf16(
      __builtin_bit_cast(bf16x8, a), __builtin_bit_cast(bf16x8, b), c, 0, 0, 0);
}

static __device__ __forceinline__ void gload_lds16(const void* g, void* l) {
  __builtin_amdgcn_global_load_lds(
      (const __attribute__((address_space(1))) uint32_t*)g,
      (__attribute__((address_space(3))) uint32_t*)l, 16, 0, 0);
}

// ---------------- fp32 -> bf16 cast (vectorized) ----------------
__global__ void cvt_kernel(const float* __restrict__ in, u16* __restrict__ out, int n8) {
  int i = blockIdx.x * blockDim.x + threadIdx.x;
  if (i >= n8) return;
  const fvec4* p = (const fvec4*)(in + (size_t)i * 8);
  fvec4 a = p[0], b = p[1];
  u16x8 o;
  o[0] = f2b(a[0]); o[1] = f2b(a[1]); o[2] = f2b(a[2]); o[3] = f2b(a[3]);
  o[4] = f2b(b[0]); o[5] = f2b(b[1]); o[6] = f2b(b[2]); o[7] = f2b(b[3]);
  *(u16x8*)(out + (size_t)i * 8) = o;
}

__global__ void wcvt_kernel(const float* __restrict__ w0, const float* __restrict__ w1,
                            const float* __restrict__ w2, const float* __restrict__ w3,
                            u16* __restrict__ o0, u16* __restrict__ o1,
                            u16* __restrict__ o2, u16* __restrict__ o3, int n8) {
  int i = blockIdx.x * blockDim.x + threadIdx.x;
  if (i >= n8) return;
  const int z = blockIdx.y;
  const float* in = (z == 0) ? w0 : (z == 1) ? w1 : (z == 2) ? w2 : w3;
  u16* out = (z == 0) ? o0 : (z == 1) ? o1 : (z == 2) ? o2 : o3;
  const fvec4* p = (const fvec4*)(in + (size_t)i * 8);
  fvec4 a = p[0], b = p[1];
  u16x8 o;
  o[0] = f2b(a[0]); o[1] = f2b(a[1]); o[2] = f2b(a[2]); o[3] = f2b(a[3]);
  o[4] = f2b(b[0]); o[5] = f2b(b[1]); o[6] = f2b(b[2]); o[7] = f2b(b[3]);
  *(u16x8*)(out + (size_t)i * 8) = o;
}

// ---------------- QKV GEMM (m97 structure) ----------------
// z=0: Q head-major, PRE-SCALED by 0.125*log2e (fp32, exact). z=1: K. z=2: V^T [h][d][t].
__global__ __launch_bounds__(256) void gemm_qkv(
    const u16* __restrict__ xb,
    const u16* __restrict__ wqb, const u16* __restrict__ wkb, const u16* __restrict__ wvb,
    const float* __restrict__ bq, const float* __restrict__ bk, const float* __restrict__ bv,
    u16* __restrict__ qh, u16* __restrict__ kh, u16* __restrict__ vt)
{
  __shared__ u16 sA[128 * 32];
  __shared__ u16 sB[128 * 32];
  const int K = C_DIM;
  const int z = blockIdx.z;
  const u16* wb = (z == 0) ? wqb : (z == 1) ? wkb : wvb;
  const float* bias = (z == 0) ? bq : (z == 1) ? bk : bv;
  const int m0 = blockIdx.x * 128;
  const int n0 = blockIdx.y * 128;
  const int tid = threadIdx.x;
  const int lane = tid & 63;
  const int w = tid >> 6;
  const int wm = (w >> 1) * 64;
  const int wn = (w & 1) * 64;
  const int lr = lane & 15;
  const int lk = (lane >> 4) * 8;

  f32x4 acc[4][4];
#pragma unroll
  for (int m = 0; m < 4; ++m)
#pragma unroll
    for (int n = 0; n < 4; ++n) acc[m][n] = (f32x4){0.f, 0.f, 0.f, 0.f};

  const int srow = tid >> 2;
  const int scol = (tid & 3) * 8;
  const u16* gA = xb + (size_t)(m0 + srow) * K + scol;
  const u16* gB = wb + (size_t)(n0 + srow) * K + scol;

  for (int k0 = 0; k0 < K; k0 += 32) {
    gload_lds16(gA + k0,          &sA[tid * 8]);
    gload_lds16(gA + 64 * K + k0, &sA[2048 + tid * 8]);
    gload_lds16(gB + k0,          &sB[tid * 8]);
    gload_lds16(gB + 64 * K + k0, &sB[2048 + tid * 8]);
    __syncthreads();
    u16x8 af[4], bfr[4];
#pragma unroll
    for (int m = 0; m < 4; ++m) af[m]  = *(const u16x8*)&sA[(wm + m * 16 + lr) * 32 + lk];
#pragma unroll
    for (int n = 0; n < 4; ++n) bfr[n] = *(const u16x8*)&sB[(wn + n * 16 + lr) * 32 + lk];
#pragma unroll
    for (int m = 0; m < 4; ++m)
#pragma unroll
      for (int n = 0; n < 4; ++n) acc[m][n] = mfma16(af[m], bfr[n], acc[m][n]);
    __syncthreads();
  }

  const int lg = lane >> 4;
#pragma unroll
  for (int n = 0; n < 4; ++n) {
    const int o = n0 + wn + n * 16 + lr;
    const float bb = bias[o];
    const int h = o >> 6;
    const int d = o & 63;
#pragma unroll
    for (int m = 0; m < 4; ++m) {
      const int tb = m0 + wm + m * 16 + lg * 4;
      if (z == 2) {
        uint2 pk;
        pk.x = cvtpk(acc[m][n][0] + bb, acc[m][n][1] + bb);
        pk.y = cvtpk(acc[m][n][2] + bb, acc[m][n][3] + bb);
        *(uint2*)&vt[(size_t)o * T_LEN + tb] = pk;
      } else if (z == 0) {
#pragma unroll
        for (int r = 0; r < 4; ++r)
          qh[((size_t)h * T_LEN + tb + r) * 64 + d] = f2b((acc[m][n][r] + bb) * CLOG2E);
      } else {
#pragma unroll
        for (int r = 0; r < 4; ++r)
          kh[((size_t)h * T_LEN + tb + r) * 64 + d] = f2b(acc[m][n][r] + bb);
      }
    }
  }
}

// ---------------- output projection ----------------
__global__ __launch_bounds__(256) void gemm_proj(
    const u16* __restrict__ yb, const u16* __restrict__ wpb,
    const float* __restrict__ bp, float* __restrict__ out)
{
  __shared__ u16 sA[128 * 32];
  __shared__ u16 sB[128 * 32];
  const int K = C_DIM;
  const int m0 = blockIdx.x * 128;
  const int n0 = blockIdx.y * 128;
  const int tid = threadIdx.x;
  const int lane = tid & 63;
  const int w = tid >> 6;
  const int wm = (w >> 1) * 64;
  const int wn = (w & 1) * 64;
  const int lr = lane & 15;
  const int lk = (lane >> 4) * 8;

  f32x4 acc[4][4];
#pragma unroll
  for (int m = 0; m < 4; ++m)
#pragma unroll
    for (int n = 0; n < 4; ++n) acc[m][n] = (f32x4){0.f, 0.f, 0.f, 0.f};

  const int srow = tid >> 2;
  const int scol = (tid & 3) * 8;
  const u16* gA = yb  + (size_t)(m0 + srow) * K + scol;
  const u16* gB = wpb + (size_t)(n0 + srow) * K + scol;

  for (int k0 = 0; k0 < K; k0 += 32) {
    gload_lds16(gA + k0,          &sA[tid * 8]);
    gload_lds16(gA + 64 * K + k0, &sA[2048 + tid * 8]);
    gload_lds16(gB + k0,          &sB[tid * 8]);
    gload_lds16(gB + 64 * K + k0, &sB[2048 + tid * 8]);
    __syncthreads();
    u16x8 af[4], bfr[4];
#pragma unroll
    for (int m = 0; m < 4; ++m) af[m]  = *(const u16x8*)&sA[(wm + m * 16 + lr) * 32 + lk];
#pragma unroll
    for (int n = 0; n < 4; ++n) bfr[n] = *(const u16x8*)&sB[(wn + n * 16 + lr) * 32 + lk];
#pragma unroll
    for (int m = 0; m < 4; ++m)
#pragma unroll
      for (int n = 0; n < 4; ++n) acc[m][n] = mfma16(af[m], bfr[n], acc[m][n]);
    __syncthreads();
  }

  const int lg = lane >> 4;
#pragma unroll
  for (int n = 0; n < 4; ++n) {
    const int o = n0 + wn + n * 16 + lr;
    const float bb = bp[o];
#pragma unroll
    for (int m = 0; m < 4; ++m) {
      const int tb = m0 + wm + m * 16 + lg * 4;
#pragma unroll
      for (int r = 0; r < 4; ++r)
        out[(size_t)(tb + r) * C_DIM + o] = acc[m][n][r] + bb;
    }
  }
}

// ---------------- flash attention v4 ----------------
// = R2's proven structure (paired q-tiles (63-bx, bx) => uniform 65 kv-tiles/block;
//   K AND V LDS-staged, double-buffered, XOR-swizzled, 1 barrier/tile; T13 defer-max)
// + Q pre-scaled in GEMM epilogue (no per-element scale mul)
// + cvt_pk bf16 packing (T12 primitive)
// + XCD-aware block swizzle (T1): 1-D grid 512, each XCD owns 2 heads' K/V.
__global__ __launch_bounds__(256) void attn_kernel(
    const u16* __restrict__ qh, const u16* __restrict__ kh, const u16* __restrict__ vt,
    u16* __restrict__ y)
{
  __shared__ char skb[2][8192];
  __shared__ char svb[2][8192];
  __shared__ u16 pp[4][16][LSTR];
  // XCD swizzle: consecutive blockIdx round-robin over 8 XCDs; remap so each
  // XCD gets a contiguous chunk of 64 = 2 full heads (nwg=512, nwg%8==0: bijective).
  const int bid = blockIdx.x;
  const int s = (bid & 7) * 64 + (bid >> 3);
  const int h = s >> 5;
  const int bx = s & 31;
  const int tid = threadIdx.x;
  const int lane = tid & 63;
  const int w = tid >> 6;
  const int lr = lane & 15;
  const int lg = lane >> 4;
  const int sw = (lr & 7) << 4;

  const int srow = tid >> 2;            // 0..63
  const int scb = (tid & 3) * 32;       // byte col within 128B row
  const int wo0 = srow * 128 + (scb ^ ((srow & 7) << 4));
  const int wo1 = srow * 128 + ((scb + 16) ^ ((srow & 7) << 4));
  const u16* gkbase = kh + ((size_t)h * T_LEN + srow) * 64 + (tid & 3) * 16;
  const u16* gvbase = vt + ((size_t)h * 64 + srow) * T_LEN + (tid & 3) * 16;
  u16* ppw = &pp[w][0][0];

  for (int ph = 0; ph < 2; ++ph) {
    const int qb = ph ? bx : (63 - bx);
    const int nt = qb + 1;
    const int qt0 = qb * 64 + w * 16;

    const u16* qbase = qh + ((size_t)h * T_LEN + qt0 + lr) * 64 + lg * 8;
    u16x8 qf0 = *(const u16x8*)(qbase);
    u16x8 qf1 = *(const u16x8*)(qbase + 32);

    f32x4 oacc[4];
#pragma unroll
    for (int i = 0; i < 4; ++i) oacc[i] = (f32x4){0.f, 0.f, 0.f, 0.f};
    float mrow = -1e30f, lsum = 0.f;

    // prologue: tile 0 into buffer 0
    u16x8 ka = *(const u16x8*)(gkbase);
    u16x8 kb = *(const u16x8*)(gkbase + 8);
    u16x8 va = *(const u16x8*)(gvbase);
    u16x8 vb = *(const u16x8*)(gvbase + 8);
    __syncthreads();   // previous phase's LDS reads complete
    *(u16x8*)(skb[0] + wo0) = ka; *(u16x8*)(skb[0] + wo1) = kb;
    *(u16x8*)(svb[0] + wo0) = va; *(u16x8*)(svb[0] + wo1) = vb;
    int cur = 0;

    for (int t = 0; t < nt; ++t) {
      if (t + 1 < nt) {   // reg-stage next tile early (T14)
        const size_t ko = (size_t)(t + 1) * 4096;
        ka = *(const u16x8*)(gkbase + ko);
        kb = *(const u16x8*)(gkbase + ko + 8);
        va = *(const u16x8*)(gvbase + (t + 1) * 64);
        vb = *(const u16x8*)(gvbase + (t + 1) * 64 + 8);
      }
      __syncthreads();   // buffer[cur] writes (prev iter) visible
      const char* skc = skb[cur];
      const char* svc = svb[cur];

      // S^T = K * Q^T  (scale already folded into Q)
      f32x4 sacc[4];
#pragma unroll
      for (int i = 0; i < 4; ++i) {
        const int ro = (i * 16 + lr) * 128;
        u16x8 a0 = *(const u16x8*)(skc + ro + ((lg * 16) ^ sw));
        u16x8 a1 = *(const u16x8*)(skc + ro + ((lg * 16 + 64) ^ sw));
        f32x4 zz = (f32x4){0.f, 0.f, 0.f, 0.f};
        zz = mfma16(a0, qf0, zz);
        zz = mfma16(a1, qf1, zz);
        sacc[i] = zz;
      }

      float pvv[4][4];
      float pm = -1e30f;
      if (t == nt - 1) {               // diagonal tile: causal mask
        const int qg = qt0 + lr;
        const int kt0 = t * 64;
#pragma unroll
        for (int i = 0; i < 4; ++i) {
#pragma unroll
          for (int r = 0; r < 4; ++r) {
            const int kt = kt0 + i * 16 + lg * 4 + r;
            pvv[i][r] = (kt <= qg) ? sacc[i][r] : -1e30f;
          }
          pm = fmaxf(pm, fmaxf(fmaxf(pvv[i][0], pvv[i][1]), fmaxf(pvv[i][2], pvv[i][3])));
        }
      } else {
#pragma unroll
        for (int i = 0; i < 4; ++i) {
#pragma unroll
          for (int r = 0; r < 4; ++r) pvv[i][r] = sacc[i][r];
          pm = fmaxf(pm, fmaxf(fmaxf(pvv[i][0], pvv[i][1]), fmaxf(pvv[i][2], pvv[i][3])));
        }
      }
      pm = fmaxf(pm, __shfl_xor(pm, 16));
      pm = fmaxf(pm, __shfl_xor(pm, 32));

      if (!__all(pm <= mrow)) {        // defer-max (T13)
        const float mnew = fmaxf(mrow, pm);
        const float sc = exp2f(mrow - mnew);
        lsum *= sc;
#pragma unroll
        for (int i = 0; i < 4; ++i) oacc[i] *= sc;
        mrow = mnew;
      }

      float tsum = 0.f;
#pragma unroll
      for (int i = 0; i < 4; ++i) {
        float e0 = exp2f(pvv[i][0] - mrow);
        float e1 = exp2f(pvv[i][1] - mrow);
        float e2 = exp2f(pvv[i][2] - mrow);
        float e3 = exp2f(pvv[i][3] - mrow);
        tsum += (e0 + e1) + (e2 + e3);
        uint2 pk;
        pk.x = cvtpk(e0, e1);
        pk.y = cvtpk(e2, e3);
        *(uint2*)&ppw[lr * LSTR + i * 16 + lg * 4] = pk;
      }
      tsum += __shfl_xor(tsum, 16);
      tsum += __shfl_xor(tsum, 32);
      lsum += tsum;

      // O^T += V^T * P^T
#pragma unroll
      for (int ks = 0; ks < 2; ++ks) {
        u16x8 pf = *(const u16x8*)&ppw[lr * LSTR + lg * 8 + ks * 32];
#pragma unroll
        for (int dblk = 0; dblk < 4; ++dblk) {
          const int ro = (dblk * 16 + lr) * 128;
          u16x8 vf = *(const u16x8*)(svc + ro + ((lg * 16 + ks * 64) ^ sw));
          oacc[dblk] = mfma16(vf, pf, oacc[dblk]);
        }
      }

      if (t + 1 < nt) {   // write prefetched tile into alternate buffer
        char* dk = skb[cur ^ 1];
        char* dv = svb[cur ^ 1];
        *(u16x8*)(dk + wo0) = ka; *(u16x8*)(dk + wo1) = kb;
        *(u16x8*)(dv + wo0) = va; *(u16x8*)(dv + wo1) = vb;
      }
      cur ^= 1;
    }

    const float inv = 1.0f / lsum;
#pragma unroll
    for (int dblk = 0; dblk < 4; ++dblk) {
      uint2 pk;
      pk.x = cvtpk(oacc[dblk][0] * inv, oacc[dblk][1] * inv);
      pk.y = cvtpk(oacc[dblk][2] * inv, oacc[dblk][3] * inv);
      *(uint2*)&y[(size_t)(qt0 + lr) * C_DIM + h * 64 + dblk * 16 + lg * 4] = pk;
    }
  }
}

extern "C" void kernel_launch(void* const* d_in, const int* in_sizes, int n_in,
                              void* d_out, int out_size, void* d_ws, size_t ws_size,
                              hipStream_t stream) {
  const float* x  = (const float*)d_in[0];
  const float* wq = (const float*)d_in[1];
  const float* bq = (const float*)d_in[2];
  const float* wk = (const float*)d_in[3];
  const float* bk = (const float*)d_in[4];
  const float* wv = (const float*)d_in[5];
  const float* bv = (const float*)d_in[6];
  const float* wp = (const float*)d_in[7];
  const float* bp = (const float*)d_in[8];

  char* ws = (char*)d_ws;
  const size_t MB = 1024 * 1024;
  u16* xb  = (u16*)(ws + 0 * MB);
  u16* wqb = (u16*)(ws + 8 * MB);
  u16* wkb = (u16*)(ws + 10 * MB);
  u16* wvb = (u16*)(ws + 12 * MB);
  u16* wpb = (u16*)(ws + 14 * MB);
  u16* qh  = (u16*)(ws + 16 * MB);
  u16* kh  = (u16*)(ws + 24 * MB);
  u16* vt  = (u16*)(ws + 32 * MB);
  u16* y   = (u16*)(ws + 40 * MB);

  cvt_kernel<<<dim3(2048), dim3(256), 0, stream>>>(x, xb, 524288);
  wcvt_kernel<<<dim3(512, 4), dim3(256), 0, stream>>>(
      wq, wk, wv, wp, wqb, wkb, wvb, wpb, 131072);

  gemm_qkv<<<dim3(32, 8, 3), dim3(256), 0, stream>>>(
      xb, wqb, wkb, wvb, bq, bk, bv, qh, kh, vt);

  attn_kernel<<<dim3(512), dim3(256), 0, stream>>>(qh, kh, vt, y);

  gemm_proj<<<dim3(32, 8), dim3(256), 0, stream>>>(y, wpb, bp, (float*)d_out);
}

// Round 6
// 156.197 us; speedup vs baseline: 2.0129x; 1.0029x over previous
//
#include <hip/hip_runtime.h>
#include <stdint.h>

#define T_LEN 4096
#define C_DIM 1024
#define NH 16
#define LSTR 72
#define CLOG2E 0.18033688011112042f   // 0.125 * log2(e)

typedef uint16_t u16;
typedef __attribute__((ext_vector_type(4))) float f32x4;
typedef __attribute__((ext_vector_type(8))) __bf16 bf16x8;
typedef __attribute__((ext_vector_type(8))) uint16_t u16x8;
typedef __attribute__((ext_vector_type(4))) uint16_t u16x4;
typedef __attribute__((ext_vector_type(4))) float fvec4;

static __device__ __forceinline__ u16 f2b(float f) {
  union { float f; uint32_t u; } v; v.f = f;
  uint32_t u = v.u;
  return (u16)((u + 0x7fffu + ((u >> 16) & 1u)) >> 16);
}

// packed fp32->bf16x2 (RNE) — inline asm, no builtin on gfx950
static __device__ __forceinline__ uint32_t cvtpk(float lo, float hi) {
  uint32_t r;
  asm("v_cvt_pk_bf16_f32 %0, %1, %2" : "=v"(r) : "v"(lo), "v"(hi));
  return r;
}

static __device__ __forceinline__ f32x4 mfma16(u16x8 a, u16x8 b, f32x4 c) {
  return __builtin_amdgcn_mfma_f32_16x16x32_bf16(
      __builtin_bit_cast(bf16x8, a), __builtin_bit_cast(bf16x8, b), c, 0, 0, 0);
}

static __device__ __forceinline__ void gload_lds16(const void* g, void* l) {
  __builtin_amdgcn_global_load_lds(
      (const __attribute__((address_space(1))) uint32_t*)g,
      (__attribute__((address_space(3))) uint32_t*)l, 16, 0, 0);
}

// ---------------- fp32 -> bf16 cast (vectorized) ----------------
__global__ void cvt_kernel(const float* __restrict__ in, u16* __restrict__ out, int n8) {
  int i = blockIdx.x * blockDim.x + threadIdx.x;
  if (i >= n8) return;
  const fvec4* p = (const fvec4*)(in + (size_t)i * 8);
  fvec4 a = p[0], b = p[1];
  u16x8 o;
  o[0] = f2b(a[0]); o[1] = f2b(a[1]); o[2] = f2b(a[2]); o[3] = f2b(a[3]);
  o[4] = f2b(b[0]); o[5] = f2b(b[1]); o[6] = f2b(b[2]); o[7] = f2b(b[3]);
  *(u16x8*)(out + (size_t)i * 8) = o;
}

__global__ void wcvt_kernel(const float* __restrict__ w0, const float* __restrict__ w1,
                            const float* __restrict__ w2, const float* __restrict__ w3,
                            u16* __restrict__ o0, u16* __restrict__ o1,
                            u16* __restrict__ o2, u16* __restrict__ o3, int n8) {
  int i = blockIdx.x * blockDim.x + threadIdx.x;
  if (i >= n8) return;
  const int z = blockIdx.y;
  const float* in = (z == 0) ? w0 : (z == 1) ? w1 : (z == 2) ? w2 : w3;
  u16* out = (z == 0) ? o0 : (z == 1) ? o1 : (z == 2) ? o2 : o3;
  const fvec4* p = (const fvec4*)(in + (size_t)i * 8);
  fvec4 a = p[0], b = p[1];
  u16x8 o;
  o[0] = f2b(a[0]); o[1] = f2b(a[1]); o[2] = f2b(a[2]); o[3] = f2b(a[3]);
  o[4] = f2b(b[0]); o[5] = f2b(b[1]); o[6] = f2b(b[2]); o[7] = f2b(b[3]);
  *(u16x8*)(out + (size_t)i * 8) = o;
}

// ---------------- QKV GEMM (m97 structure) ----------------
// z=0: Q head-major, PRE-SCALED by 0.125*log2e (fp32, exact). z=1: K. z=2: V^T [h][d][t].
__global__ __launch_bounds__(256) void gemm_qkv(
    const u16* __restrict__ xb,
    const u16* __restrict__ wqb, const u16* __restrict__ wkb, const u16* __restrict__ wvb,
    const float* __restrict__ bq, const float* __restrict__ bk, const float* __restrict__ bv,
    u16* __restrict__ qh, u16* __restrict__ kh, u16* __restrict__ vt)
{
  __shared__ u16 sA[128 * 32];
  __shared__ u16 sB[128 * 32];
  const int K = C_DIM;
  const int z = blockIdx.z;
  const u16* wb = (z == 0) ? wqb : (z == 1) ? wkb : wvb;
  const float* bias = (z == 0) ? bq : (z == 1) ? bk : bv;
  const int m0 = blockIdx.x * 128;
  const int n0 = blockIdx.y * 128;
  const int tid = threadIdx.x;
  const int lane = tid & 63;
  const int w = tid >> 6;
  const int wm = (w >> 1) * 64;
  const int wn = (w & 1) * 64;
  const int lr = lane & 15;
  const int lk = (lane >> 4) * 8;

  f32x4 acc[4][4];
#pragma unroll
  for (int m = 0; m < 4; ++m)
#pragma unroll
    for (int n = 0; n < 4; ++n) acc[m][n] = (f32x4){0.f, 0.f, 0.f, 0.f};

  const int srow = tid >> 2;
  const int scol = (tid & 3) * 8;
  const u16* gA = xb + (size_t)(m0 + srow) * K + scol;
  const u16* gB = wb + (size_t)(n0 + srow) * K + scol;

  for (int k0 = 0; k0 < K; k0 += 32) {
    gload_lds16(gA + k0,          &sA[tid * 8]);
    gload_lds16(gA + 64 * K + k0, &sA[2048 + tid * 8]);
    gload_lds16(gB + k0,          &sB[tid * 8]);
    gload_lds16(gB + 64 * K + k0, &sB[2048 + tid * 8]);
    __syncthreads();
    u16x8 af[4], bfr[4];
#pragma unroll
    for (int m = 0; m < 4; ++m) af[m]  = *(const u16x8*)&sA[(wm + m * 16 + lr) * 32 + lk];
#pragma unroll
    for (int n = 0; n < 4; ++n) bfr[n] = *(const u16x8*)&sB[(wn + n * 16 + lr) * 32 + lk];
#pragma unroll
    for (int m = 0; m < 4; ++m)
#pragma unroll
      for (int n = 0; n < 4; ++n) acc[m][n] = mfma16(af[m], bfr[n], acc[m][n]);
    __syncthreads();
  }

  const int lg = lane >> 4;
#pragma unroll
  for (int n = 0; n < 4; ++n) {
    const int o = n0 + wn + n * 16 + lr;
    const float bb = bias[o];
    const int h = o >> 6;
    const int d = o & 63;
#pragma unroll
    for (int m = 0; m < 4; ++m) {
      const int tb = m0 + wm + m * 16 + lg * 4;
      if (z == 2) {
        uint2 pk;
        pk.x = cvtpk(acc[m][n][0] + bb, acc[m][n][1] + bb);
        pk.y = cvtpk(acc[m][n][2] + bb, acc[m][n][3] + bb);
        *(uint2*)&vt[(size_t)o * T_LEN + tb] = pk;
      } else if (z == 0) {
#pragma unroll
        for (int r = 0; r < 4; ++r)
          qh[((size_t)h * T_LEN + tb + r) * 64 + d] = f2b((acc[m][n][r] + bb) * CLOG2E);
      } else {
#pragma unroll
        for (int r = 0; r < 4; ++r)
          kh[((size_t)h * T_LEN + tb + r) * 64 + d] = f2b(acc[m][n][r] + bb);
      }
    }
  }
}

// ---------------- output projection ----------------
__global__ __launch_bounds__(256) void gemm_proj(
    const u16* __restrict__ yb, const u16* __restrict__ wpb,
    const float* __restrict__ bp, float* __restrict__ out)
{
  __shared__ u16 sA[128 * 32];
  __shared__ u16 sB[128 * 32];
  const int K = C_DIM;
  const int m0 = blockIdx.x * 128;
  const int n0 = blockIdx.y * 128;
  const int tid = threadIdx.x;
  const int lane = tid & 63;
  const int w = tid >> 6;
  const int wm = (w >> 1) * 64;
  const int wn = (w & 1) * 64;
  const int lr = lane & 15;
  const int lk = (lane >> 4) * 8;

  f32x4 acc[4][4];
#pragma unroll
  for (int m = 0; m < 4; ++m)
#pragma unroll
    for (int n = 0; n < 4; ++n) acc[m][n] = (f32x4){0.f, 0.f, 0.f, 0.f};

  const int srow = tid >> 2;
  const int scol = (tid & 3) * 8;
  const u16* gA = yb  + (size_t)(m0 + srow) * K + scol;
  const u16* gB = wpb + (size_t)(n0 + srow) * K + scol;

  for (int k0 = 0; k0 < K; k0 += 32) {
    gload_lds16(gA + k0,          &sA[tid * 8]);
    gload_lds16(gA + 64 * K + k0, &sA[2048 + tid * 8]);
    gload_lds16(gB + k0,          &sB[tid * 8]);
    gload_lds16(gB + 64 * K + k0, &sB[2048 + tid * 8]);
    __syncthreads();
    u16x8 af[4], bfr[4];
#pragma unroll
    for (int m = 0; m < 4; ++m) af[m]  = *(const u16x8*)&sA[(wm + m * 16 + lr) * 32 + lk];
#pragma unroll
    for (int n = 0; n < 4; ++n) bfr[n] = *(const u16x8*)&sB[(wn + n * 16 + lr) * 32 + lk];
#pragma unroll
    for (int m = 0; m < 4; ++m)
#pragma unroll
      for (int n = 0; n < 4; ++n) acc[m][n] = mfma16(af[m], bfr[n], acc[m][n]);
    __syncthreads();
  }

  const int lg = lane >> 4;
#pragma unroll
  for (int n = 0; n < 4; ++n) {
    const int o = n0 + wn + n * 16 + lr;
    const float bb = bp[o];
#pragma unroll
    for (int m = 0; m < 4; ++m) {
      const int tb = m0 + wm + m * 16 + lg * 4;
#pragma unroll
      for (int r = 0; r < 4; ++r)
        out[(size_t)(tb + r) * C_DIM + o] = acc[m][n][r] + bb;
    }
  }
}

// ---------------- flash attention v6 ----------------
// = R4 (proven): paired q-tiles, K+V LDS dbuf, XOR swizzle, XCD swizzle, T13,
//   __shfl_xor reductions (permlane asm REVERTED — unverified semantics broke R5)
// + prefetch issued AFTER the barrier (vmcnt drain off critical path)
// + s_setprio(1) around MFMA clusters (T5).
__global__ __launch_bounds__(256) void attn_kernel(
    const u16* __restrict__ qh, const u16* __restrict__ kh, const u16* __restrict__ vt,
    u16* __restrict__ y)
{
  __shared__ char skb[2][8192];
  __shared__ char svb[2][8192];
  __shared__ u16 pp[4][16][LSTR];
  const int bid = blockIdx.x;
  const int s = (bid & 7) * 64 + (bid >> 3);   // XCD swizzle: 2 heads per XCD
  const int h = s >> 5;
  const int bx = s & 31;
  const int tid = threadIdx.x;
  const int lane = tid & 63;
  const int w = tid >> 6;
  const int lr = lane & 15;
  const int lg = lane >> 4;
  const int sw = (lr & 7) << 4;

  const int srow = tid >> 2;            // 0..63
  const int scb = (tid & 3) * 32;       // byte col within 128B row
  const int wo0 = srow * 128 + (scb ^ ((srow & 7) << 4));
  const int wo1 = srow * 128 + ((scb + 16) ^ ((srow & 7) << 4));
  const u16* gkbase = kh + ((size_t)h * T_LEN + srow) * 64 + (tid & 3) * 16;
  const u16* gvbase = vt + ((size_t)h * 64 + srow) * T_LEN + (tid & 3) * 16;
  u16* ppw = &pp[w][0][0];

  for (int ph = 0; ph < 2; ++ph) {
    const int qb = ph ? bx : (63 - bx);
    const int nt = qb + 1;
    const int qt0 = qb * 64 + w * 16;

    const u16* qbase = qh + ((size_t)h * T_LEN + qt0 + lr) * 64 + lg * 8;
    u16x8 qf0 = *(const u16x8*)(qbase);
    u16x8 qf1 = *(const u16x8*)(qbase + 32);

    f32x4 oacc[4];
#pragma unroll
    for (int i = 0; i < 4; ++i) oacc[i] = (f32x4){0.f, 0.f, 0.f, 0.f};
    float mrow = -1e30f, lsum = 0.f;

    // prologue: tile 0 into buffer 0
    u16x8 ka = *(const u16x8*)(gkbase);
    u16x8 kb = *(const u16x8*)(gkbase + 8);
    u16x8 va = *(const u16x8*)(gvbase);
    u16x8 vb = *(const u16x8*)(gvbase + 8);
    __syncthreads();   // previous phase's LDS reads complete
    *(u16x8*)(skb[0] + wo0) = ka; *(u16x8*)(skb[0] + wo1) = kb;
    *(u16x8*)(svb[0] + wo0) = va; *(u16x8*)(svb[0] + wo1) = vb;
    int cur = 0;

    for (int t = 0; t < nt; ++t) {
      __syncthreads();   // buffer[cur] writes visible
      // issue next-tile loads AFTER the barrier: latency spans this tile's compute,
      // vmcnt wait sinks to the ds_writes at the tail (not the barrier drain).
      if (t + 1 < nt) {
        const size_t ko = (size_t)(t + 1) * 4096;
        ka = *(const u16x8*)(gkbase + ko);
        kb = *(const u16x8*)(gkbase + ko + 8);
        va = *(const u16x8*)(gvbase + (t + 1) * 64);
        vb = *(const u16x8*)(gvbase + (t + 1) * 64 + 8);
      }
      const char* skc = skb[cur];
      const char* svc = svb[cur];

      // S^T = K * Q^T  (scale already folded into Q)
      f32x4 sacc[4];
      __builtin_amdgcn_s_setprio(1);
#pragma unroll
      for (int i = 0; i < 4; ++i) {
        const int ro = (i * 16 + lr) * 128;
        u16x8 a0 = *(const u16x8*)(skc + ro + ((lg * 16) ^ sw));
        u16x8 a1 = *(const u16x8*)(skc + ro + ((lg * 16 + 64) ^ sw));
        f32x4 zz = (f32x4){0.f, 0.f, 0.f, 0.f};
        zz = mfma16(a0, qf0, zz);
        zz = mfma16(a1, qf1, zz);
        sacc[i] = zz;
      }
      __builtin_amdgcn_s_setprio(0);

      float pvv[4][4];
      float pm = -1e30f;
      if (t == nt - 1) {               // diagonal tile: causal mask
        const int qg = qt0 + lr;
        const int kt0 = t * 64;
#pragma unroll
        for (int i = 0; i < 4; ++i) {
#pragma unroll
          for (int r = 0; r < 4; ++r) {
            const int kt = kt0 + i * 16 + lg * 4 + r;
            pvv[i][r] = (kt <= qg) ? sacc[i][r] : -1e30f;
          }
          pm = fmaxf(pm, fmaxf(fmaxf(pvv[i][0], pvv[i][1]), fmaxf(pvv[i][2], pvv[i][3])));
        }
      } else {
#pragma unroll
        for (int i = 0; i < 4; ++i) {
#pragma unroll
          for (int r = 0; r < 4; ++r) pvv[i][r] = sacc[i][r];
          pm = fmaxf(pm, fmaxf(fmaxf(pvv[i][0], pvv[i][1]), fmaxf(pvv[i][2], pvv[i][3])));
        }
      }
      pm = fmaxf(pm, __shfl_xor(pm, 16));
      pm = fmaxf(pm, __shfl_xor(pm, 32));

      if (!__all(pm <= mrow)) {        // defer-max (T13)
        const float mnew = fmaxf(mrow, pm);
        const float sc = exp2f(mrow - mnew);
        lsum *= sc;
#pragma unroll
        for (int i = 0; i < 4; ++i) oacc[i] *= sc;
        mrow = mnew;
      }

      float tsum = 0.f;
#pragma unroll
      for (int i = 0; i < 4; ++i) {
        float e0 = exp2f(pvv[i][0] - mrow);
        float e1 = exp2f(pvv[i][1] - mrow);
        float e2 = exp2f(pvv[i][2] - mrow);
        float e3 = exp2f(pvv[i][3] - mrow);
        tsum += (e0 + e1) + (e2 + e3);
        uint2 pk;
        pk.x = cvtpk(e0, e1);
        pk.y = cvtpk(e2, e3);
        *(uint2*)&ppw[lr * LSTR + i * 16 + lg * 4] = pk;
      }
      tsum += __shfl_xor(tsum, 16);
      tsum += __shfl_xor(tsum, 32);
      lsum += tsum;

      // O^T += V^T * P^T
      __builtin_amdgcn_s_setprio(1);
#pragma unroll
      for (int ks = 0; ks < 2; ++ks) {
        u16x8 pf = *(const u16x8*)&ppw[lr * LSTR + lg * 8 + ks * 32];
#pragma unroll
        for (int dblk = 0; dblk < 4; ++dblk) {
          const int ro = (dblk * 16 + lr) * 128;
          u16x8 vf = *(const u16x8*)(svc + ro + ((lg * 16 + ks * 64) ^ sw));
          oacc[dblk] = mfma16(vf, pf, oacc[dblk]);
        }
      }
      __builtin_amdgcn_s_setprio(0);

      if (t + 1 < nt) {   // write prefetched tile into alternate buffer
        char* dk = skb[cur ^ 1];
        char* dv = svb[cur ^ 1];
        *(u16x8*)(dk + wo0) = ka; *(u16x8*)(dk + wo1) = kb;
        *(u16x8*)(dv + wo0) = va; *(u16x8*)(dv + wo1) = vb;
      }
      cur ^= 1;
    }

    const float inv = 1.0f / lsum;
#pragma unroll
    for (int dblk = 0; dblk < 4; ++dblk) {
      uint2 pk;
      pk.x = cvtpk(oacc[dblk][0] * inv, oacc[dblk][1] * inv);
      pk.y = cvtpk(oacc[dblk][2] * inv, oacc[dblk][3] * inv);
      *(uint2*)&y[(size_t)(qt0 + lr) * C_DIM + h * 64 + dblk * 16 + lg * 4] = pk;
    }
  }
}

extern "C" void kernel_launch(void* const* d_in, const int* in_sizes, int n_in,
                              void* d_out, int out_size, void* d_ws, size_t ws_size,
                              hipStream_t stream) {
  const float* x  = (const float*)d_in[0];
  const float* wq = (const float*)d_in[1];
  const float* bq = (const float*)d_in[2];
  const float* wk = (const float*)d_in[3];
  const float* bk = (const float*)d_in[4];
  const float* wv = (const float*)d_in[5];
  const float* bv = (const float*)d_in[6];
  const float* wp = (const float*)d_in[7];
  const float* bp = (const float*)d_in[8];

  char* ws = (char*)d_ws;
  const size_t MB = 1024 * 1024;
  u16* xb  = (u16*)(ws + 0 * MB);
  u16* wqb = (u16*)(ws + 8 * MB);
  u16* wkb = (u16*)(ws + 10 * MB);
  u16* wvb = (u16*)(ws + 12 * MB);
  u16* wpb = (u16*)(ws + 14 * MB);
  u16* qh  = (u16*)(ws + 16 * MB);
  u16* kh  = (u16*)(ws + 24 * MB);
  u16* vt  = (u16*)(ws + 32 * MB);
  u16* y   = (u16*)(ws + 40 * MB);

  cvt_kernel<<<dim3(2048), dim3(256), 0, stream>>>(x, xb, 524288);
  wcvt_kernel<<<dim3(512, 4), dim3(256), 0, stream>>>(
      wq, wk, wv, wp, wqb, wkb, wvb, wpb, 131072);

  gemm_qkv<<<dim3(32, 8, 3), dim3(256), 0, stream>>>(
      xb, wqb, wkb, wvb, bq, bk, bv, qh, kh, vt);

  attn_kernel<<<dim3(512), dim3(256), 0, stream>>>(qh, kh, vt, y);

  gemm_proj<<<dim3(32, 8), dim3(256), 0, stream>>>(y, wpb, bp, (float*)d_out);
}

// Round 7
// 151.872 us; speedup vs baseline: 2.0702x; 1.0285x over previous
//
#include <hip/hip_runtime.h>
#include <stdint.h>

#define T_LEN 4096
#define C_DIM 1024
#define NH 16
#define LSTR 72
#define CLOG2E 0.18033688011112042f   // 0.125 * log2(e)

typedef uint16_t u16;
typedef __attribute__((ext_vector_type(4))) float f32x4;
typedef __attribute__((ext_vector_type(8))) __bf16 bf16x8;
typedef __attribute__((ext_vector_type(8))) uint16_t u16x8;
typedef __attribute__((ext_vector_type(4))) uint16_t u16x4;
typedef __attribute__((ext_vector_type(4))) float fvec4;

static __device__ __forceinline__ u16 f2b(float f) {
  union { float f; uint32_t u; } v; v.f = f;
  uint32_t u = v.u;
  return (u16)((u + 0x7fffu + ((u >> 16) & 1u)) >> 16);
}

// packed fp32->bf16x2 (RNE) — inline asm, no builtin on gfx950
static __device__ __forceinline__ uint32_t cvtpk(float lo, float hi) {
  uint32_t r;
  asm("v_cvt_pk_bf16_f32 %0, %1, %2" : "=v"(r) : "v"(lo), "v"(hi));
  return r;
}

static __device__ __forceinline__ f32x4 mfma16(u16x8 a, u16x8 b, f32x4 c) {
  return __builtin_amdgcn_mfma_f32_16x16x32_bf16(
      __builtin_bit_cast(bf16x8, a), __builtin_bit_cast(bf16x8, b), c, 0, 0, 0);
}

static __device__ __forceinline__ void gload_lds16(const void* g, void* l) {
  __builtin_amdgcn_global_load_lds(
      (const __attribute__((address_space(1))) uint32_t*)g,
      (__attribute__((address_space(3))) uint32_t*)l, 16, 0, 0);
}

// ---------------- fp32 -> bf16 cast (vectorized) ----------------
__global__ void cvt_kernel(const float* __restrict__ in, u16* __restrict__ out, int n8) {
  int i = blockIdx.x * blockDim.x + threadIdx.x;
  if (i >= n8) return;
  const fvec4* p = (const fvec4*)(in + (size_t)i * 8);
  fvec4 a = p[0], b = p[1];
  u16x8 o;
  o[0] = f2b(a[0]); o[1] = f2b(a[1]); o[2] = f2b(a[2]); o[3] = f2b(a[3]);
  o[4] = f2b(b[0]); o[5] = f2b(b[1]); o[6] = f2b(b[2]); o[7] = f2b(b[3]);
  *(u16x8*)(out + (size_t)i * 8) = o;
}

__global__ void wcvt_kernel(const float* __restrict__ w0, const float* __restrict__ w1,
                            const float* __restrict__ w2, const float* __restrict__ w3,
                            u16* __restrict__ o0, u16* __restrict__ o1,
                            u16* __restrict__ o2, u16* __restrict__ o3, int n8) {
  int i = blockIdx.x * blockDim.x + threadIdx.x;
  if (i >= n8) return;
  const int z = blockIdx.y;
  const float* in = (z == 0) ? w0 : (z == 1) ? w1 : (z == 2) ? w2 : w3;
  u16* out = (z == 0) ? o0 : (z == 1) ? o1 : (z == 2) ? o2 : o3;
  const fvec4* p = (const fvec4*)(in + (size_t)i * 8);
  fvec4 a = p[0], b = p[1];
  u16x8 o;
  o[0] = f2b(a[0]); o[1] = f2b(a[1]); o[2] = f2b(a[2]); o[3] = f2b(a[3]);
  o[4] = f2b(b[0]); o[5] = f2b(b[1]); o[6] = f2b(b[2]); o[7] = f2b(b[3]);
  *(u16x8*)(out + (size_t)i * 8) = o;
}

// ---------------- QKV GEMM (m97 structure) ----------------
// z=0: Q head-major, PRE-SCALED by 0.125*log2e (fp32, exact). z=1: K. z=2: V^T [h][d][t].
__global__ __launch_bounds__(256) void gemm_qkv(
    const u16* __restrict__ xb,
    const u16* __restrict__ wqb, const u16* __restrict__ wkb, const u16* __restrict__ wvb,
    const float* __restrict__ bq, const float* __restrict__ bk, const float* __restrict__ bv,
    u16* __restrict__ qh, u16* __restrict__ kh, u16* __restrict__ vt)
{
  __shared__ u16 sA[128 * 32];
  __shared__ u16 sB[128 * 32];
  const int K = C_DIM;
  const int z = blockIdx.z;
  const u16* wb = (z == 0) ? wqb : (z == 1) ? wkb : wvb;
  const float* bias = (z == 0) ? bq : (z == 1) ? bk : bv;
  const int m0 = blockIdx.x * 128;
  const int n0 = blockIdx.y * 128;
  const int tid = threadIdx.x;
  const int lane = tid & 63;
  const int w = tid >> 6;
  const int wm = (w >> 1) * 64;
  const int wn = (w & 1) * 64;
  const int lr = lane & 15;
  const int lk = (lane >> 4) * 8;

  f32x4 acc[4][4];
#pragma unroll
  for (int m = 0; m < 4; ++m)
#pragma unroll
    for (int n = 0; n < 4; ++n) acc[m][n] = (f32x4){0.f, 0.f, 0.f, 0.f};

  const int srow = tid >> 2;
  const int scol = (tid & 3) * 8;
  const u16* gA = xb + (size_t)(m0 + srow) * K + scol;
  const u16* gB = wb + (size_t)(n0 + srow) * K + scol;

  for (int k0 = 0; k0 < K; k0 += 32) {
    gload_lds16(gA + k0,          &sA[tid * 8]);
    gload_lds16(gA + 64 * K + k0, &sA[2048 + tid * 8]);
    gload_lds16(gB + k0,          &sB[tid * 8]);
    gload_lds16(gB + 64 * K + k0, &sB[2048 + tid * 8]);
    __syncthreads();
    u16x8 af[4], bfr[4];
#pragma unroll
    for (int m = 0; m < 4; ++m) af[m]  = *(const u16x8*)&sA[(wm + m * 16 + lr) * 32 + lk];
#pragma unroll
    for (int n = 0; n < 4; ++n) bfr[n] = *(const u16x8*)&sB[(wn + n * 16 + lr) * 32 + lk];
#pragma unroll
    for (int m = 0; m < 4; ++m)
#pragma unroll
      for (int n = 0; n < 4; ++n) acc[m][n] = mfma16(af[m], bfr[n], acc[m][n]);
    __syncthreads();
  }

  const int lg = lane >> 4;
#pragma unroll
  for (int n = 0; n < 4; ++n) {
    const int o = n0 + wn + n * 16 + lr;
    const float bb = bias[o];
    const int h = o >> 6;
    const int d = o & 63;
#pragma unroll
    for (int m = 0; m < 4; ++m) {
      const int tb = m0 + wm + m * 16 + lg * 4;
      if (z == 2) {
        uint2 pk;
        pk.x = cvtpk(acc[m][n][0] + bb, acc[m][n][1] + bb);
        pk.y = cvtpk(acc[m][n][2] + bb, acc[m][n][3] + bb);
        *(uint2*)&vt[(size_t)o * T_LEN + tb] = pk;
      } else if (z == 0) {
#pragma unroll
        for (int r = 0; r < 4; ++r)
          qh[((size_t)h * T_LEN + tb + r) * 64 + d] = f2b((acc[m][n][r] + bb) * CLOG2E);
      } else {
#pragma unroll
        for (int r = 0; r < 4; ++r)
          kh[((size_t)h * T_LEN + tb + r) * 64 + d] = f2b(acc[m][n][r] + bb);
      }
    }
  }
}

// ---------------- output projection ----------------
__global__ __launch_bounds__(256) void gemm_proj(
    const u16* __restrict__ yb, const u16* __restrict__ wpb,
    const float* __restrict__ bp, float* __restrict__ out)
{
  __shared__ u16 sA[128 * 32];
  __shared__ u16 sB[128 * 32];
  const int K = C_DIM;
  const int m0 = blockIdx.x * 128;
  const int n0 = blockIdx.y * 128;
  const int tid = threadIdx.x;
  const int lane = tid & 63;
  const int w = tid >> 6;
  const int wm = (w >> 1) * 64;
  const int wn = (w & 1) * 64;
  const int lr = lane & 15;
  const int lk = (lane >> 4) * 8;

  f32x4 acc[4][4];
#pragma unroll
  for (int m = 0; m < 4; ++m)
#pragma unroll
    for (int n = 0; n < 4; ++n) acc[m][n] = (f32x4){0.f, 0.f, 0.f, 0.f};

  const int srow = tid >> 2;
  const int scol = (tid & 3) * 8;
  const u16* gA = yb  + (size_t)(m0 + srow) * K + scol;
  const u16* gB = wpb + (size_t)(n0 + srow) * K + scol;

  for (int k0 = 0; k0 < K; k0 += 32) {
    gload_lds16(gA + k0,          &sA[tid * 8]);
    gload_lds16(gA + 64 * K + k0, &sA[2048 + tid * 8]);
    gload_lds16(gB + k0,          &sB[tid * 8]);
    gload_lds16(gB + 64 * K + k0, &sB[2048 + tid * 8]);
    __syncthreads();
    u16x8 af[4], bfr[4];
#pragma unroll
    for (int m = 0; m < 4; ++m) af[m]  = *(const u16x8*)&sA[(wm + m * 16 + lr) * 32 + lk];
#pragma unroll
    for (int n = 0; n < 4; ++n) bfr[n] = *(const u16x8*)&sB[(wn + n * 16 + lr) * 32 + lk];
#pragma unroll
    for (int m = 0; m < 4; ++m)
#pragma unroll
      for (int n = 0; n < 4; ++n) acc[m][n] = mfma16(af[m], bfr[n], acc[m][n]);
    __syncthreads();
  }

  const int lg = lane >> 4;
#pragma unroll
  for (int n = 0; n < 4; ++n) {
    const int o = n0 + wn + n * 16 + lr;
    const float bb = bp[o];
#pragma unroll
    for (int m = 0; m < 4; ++m) {
      const int tb = m0 + wm + m * 16 + lg * 4;
#pragma unroll
      for (int r = 0; r < 4; ++r)
        out[(size_t)(tb + r) * C_DIM + o] = acc[m][n][r] + bb;
    }
  }
}

// ---------------- flash attention v7 ----------------
// R6 structure minus the per-tile cross-lane chain:
//  * per-lane defer-max vote: __all(pm_lane <= mrow) — equivalent to reduced check
//    (mrow row-uniform); shfl reduce only inside the rare record-tile branch.
//  * lsum kept lane-local; single reduction per block at the end.
//  * grid 1024 (one q-tile/block), XCD-chunked + LPT (longest-first, heads
//    interleaved): 4 blocks/CU dispatched, 3 resident (LDS-capped).
__global__ __launch_bounds__(256) void attn_kernel(
    const u16* __restrict__ qh, const u16* __restrict__ kh, const u16* __restrict__ vt,
    u16* __restrict__ y)
{
  __shared__ char skb[2][8192];
  __shared__ char svb[2][8192];
  __shared__ u16 pp[4][16][LSTR];
  // XCD chunking + LPT: xcd = bid&7 owns heads {2*xcd, 2*xcd+1}; within chunk,
  // j = bid>>3 interleaves heads and descends q-tile length (longest first).
  const int bid = blockIdx.x;
  const int j = bid >> 3;
  const int h = ((bid & 7) << 1) + (j & 1);
  const int qb = 63 - (j >> 1);
  const int nt = qb + 1;
  const int tid = threadIdx.x;
  const int lane = tid & 63;
  const int w = tid >> 6;
  const int lr = lane & 15;
  const int lg = lane >> 4;
  const int sw = (lr & 7) << 4;
  const int qt0 = qb * 64 + w * 16;

  const int srow = tid >> 2;            // 0..63
  const int scb = (tid & 3) * 32;       // byte col within 128B row
  const int wo0 = srow * 128 + (scb ^ ((srow & 7) << 4));
  const int wo1 = srow * 128 + ((scb + 16) ^ ((srow & 7) << 4));
  const u16* gkbase = kh + ((size_t)h * T_LEN + srow) * 64 + (tid & 3) * 16;
  const u16* gvbase = vt + ((size_t)h * 64 + srow) * T_LEN + (tid & 3) * 16;
  u16* ppw = &pp[w][0][0];

  const u16* qbase = qh + ((size_t)h * T_LEN + qt0 + lr) * 64 + lg * 8;
  u16x8 qf0 = *(const u16x8*)(qbase);
  u16x8 qf1 = *(const u16x8*)(qbase + 32);

  f32x4 oacc[4];
#pragma unroll
  for (int i = 0; i < 4; ++i) oacc[i] = (f32x4){0.f, 0.f, 0.f, 0.f};
  float mrow = -1e30f, lsum = 0.f;

  // prologue: tile 0 into buffer 0
  u16x8 ka = *(const u16x8*)(gkbase);
  u16x8 kb = *(const u16x8*)(gkbase + 8);
  u16x8 va = *(const u16x8*)(gvbase);
  u16x8 vb = *(const u16x8*)(gvbase + 8);
  *(u16x8*)(skb[0] + wo0) = ka; *(u16x8*)(skb[0] + wo1) = kb;
  *(u16x8*)(svb[0] + wo0) = va; *(u16x8*)(svb[0] + wo1) = vb;
  int cur = 0;

  for (int t = 0; t < nt; ++t) {
    __syncthreads();   // buffer[cur] writes visible
    if (t + 1 < nt) {  // issue next-tile loads; latency spans this tile's compute
      const size_t ko = (size_t)(t + 1) * 4096;
      ka = *(const u16x8*)(gkbase + ko);
      kb = *(const u16x8*)(gkbase + ko + 8);
      va = *(const u16x8*)(gvbase + (t + 1) * 64);
      vb = *(const u16x8*)(gvbase + (t + 1) * 64 + 8);
    }
    const char* skc = skb[cur];
    const char* svc = svb[cur];

    // S^T = K * Q^T  (scale already folded into Q)
    f32x4 sacc[4];
    __builtin_amdgcn_s_setprio(1);
#pragma unroll
    for (int i = 0; i < 4; ++i) {
      const int ro = (i * 16 + lr) * 128;
      u16x8 a0 = *(const u16x8*)(skc + ro + ((lg * 16) ^ sw));
      u16x8 a1 = *(const u16x8*)(skc + ro + ((lg * 16 + 64) ^ sw));
      f32x4 zz = (f32x4){0.f, 0.f, 0.f, 0.f};
      zz = mfma16(a0, qf0, zz);
      zz = mfma16(a1, qf1, zz);
      sacc[i] = zz;
    }
    __builtin_amdgcn_s_setprio(0);

    float pvv[4][4];
    float pm = -1e30f;                 // PER-LANE tile max (no reduce on common path)
    if (t == nt - 1) {                 // diagonal tile: causal mask
      const int qg = qt0 + lr;
      const int kt0 = t * 64;
#pragma unroll
      for (int i = 0; i < 4; ++i) {
#pragma unroll
        for (int r = 0; r < 4; ++r) {
          const int kt = kt0 + i * 16 + lg * 4 + r;
          pvv[i][r] = (kt <= qg) ? sacc[i][r] : -1e30f;
        }
        pm = fmaxf(pm, fmaxf(fmaxf(pvv[i][0], pvv[i][1]), fmaxf(pvv[i][2], pvv[i][3])));
      }
    } else {
#pragma unroll
      for (int i = 0; i < 4; ++i) {
#pragma unroll
        for (int r = 0; r < 4; ++r) pvv[i][r] = sacc[i][r];
        pm = fmaxf(pm, fmaxf(fmaxf(pvv[i][0], pvv[i][1]), fmaxf(pvv[i][2], pvv[i][3])));
      }
    }

    // defer-max with per-lane vote: all lanes' pm <= row-uniform mrow
    // <=> every row's full max <= mrow. Record tiles (~ln(nt) of nt) reduce+rescale.
    if (!__all(pm <= mrow)) {
      float pmf = fmaxf(pm, __shfl_xor(pm, 16));
      pmf = fmaxf(pmf, __shfl_xor(pmf, 32));     // row-uniform full max
      const float mnew = fmaxf(mrow, pmf);
      const float sc = exp2f(mrow - mnew);
      lsum *= sc;
#pragma unroll
      for (int i = 0; i < 4; ++i) oacc[i] *= sc;
      mrow = mnew;
    }

    float tsum = 0.f;
#pragma unroll
    for (int i = 0; i < 4; ++i) {
      float e0 = exp2f(pvv[i][0] - mrow);
      float e1 = exp2f(pvv[i][1] - mrow);
      float e2 = exp2f(pvv[i][2] - mrow);
      float e3 = exp2f(pvv[i][3] - mrow);
      tsum += (e0 + e1) + (e2 + e3);
      uint2 pk;
      pk.x = cvtpk(e0, e1);
      pk.y = cvtpk(e2, e3);
      *(uint2*)&ppw[lr * LSTR + i * 16 + lg * 4] = pk;
    }
    lsum += tsum;                       // lane-local partial; reduced once at end

    // O^T += V^T * P^T
    __builtin_amdgcn_s_setprio(1);
#pragma unroll
    for (int ks = 0; ks < 2; ++ks) {
      u16x8 pf = *(const u16x8*)&ppw[lr * LSTR + lg * 8 + ks * 32];
#pragma unroll
      for (int dblk = 0; dblk < 4; ++dblk) {
        const int ro = (dblk * 16 + lr) * 128;
        u16x8 vf = *(const u16x8*)(svc + ro + ((lg * 16 + ks * 64) ^ sw));
        oacc[dblk] = mfma16(vf, pf, oacc[dblk]);
      }
    }
    __builtin_amdgcn_s_setprio(0);

    if (t + 1 < nt) {   // write prefetched tile into alternate buffer
      char* dk = skb[cur ^ 1];
      char* dv = svb[cur ^ 1];
      *(u16x8*)(dk + wo0) = ka; *(u16x8*)(dk + wo1) = kb;
      *(u16x8*)(dv + wo0) = va; *(u16x8*)(dv + wo1) = vb;
    }
    cur ^= 1;
  }

  // final denominator reduction (once per block, not per tile)
  lsum += __shfl_xor(lsum, 16);
  lsum += __shfl_xor(lsum, 32);
  const float inv = 1.0f / lsum;
#pragma unroll
  for (int dblk = 0; dblk < 4; ++dblk) {
    uint2 pk;
    pk.x = cvtpk(oacc[dblk][0] * inv, oacc[dblk][1] * inv);
    pk.y = cvtpk(oacc[dblk][2] * inv, oacc[dblk][3] * inv);
    *(uint2*)&y[(size_t)(qt0 + lr) * C_DIM + h * 64 + dblk * 16 + lg * 4] = pk;
  }
}

extern "C" void kernel_launch(void* const* d_in, const int* in_sizes, int n_in,
                              void* d_out, int out_size, void* d_ws, size_t ws_size,
                              hipStream_t stream) {
  const float* x  = (const float*)d_in[0];
  const float* wq = (const float*)d_in[1];
  const float* bq = (const float*)d_in[2];
  const float* wk = (const float*)d_in[3];
  const float* bk = (const float*)d_in[4];
  const float* wv = (const float*)d_in[5];
  const float* bv = (const float*)d_in[6];
  const float* wp = (const float*)d_in[7];
  const float* bp = (const float*)d_in[8];

  char* ws = (char*)d_ws;
  const size_t MB = 1024 * 1024;
  u16* xb  = (u16*)(ws + 0 * MB);
  u16* wqb = (u16*)(ws + 8 * MB);
  u16* wkb = (u16*)(ws + 10 * MB);
  u16* wvb = (u16*)(ws + 12 * MB);
  u16* wpb = (u16*)(ws + 14 * MB);
  u16* qh  = (u16*)(ws + 16 * MB);
  u16* kh  = (u16*)(ws + 24 * MB);
  u16* vt  = (u16*)(ws + 32 * MB);
  u16* y   = (u16*)(ws + 40 * MB);

  cvt_kernel<<<dim3(2048), dim3(256), 0, stream>>>(x, xb, 524288);
  wcvt_kernel<<<dim3(512, 4), dim3(256), 0, stream>>>(
      wq, wk, wv, wp, wqb, wkb, wvb, wpb, 131072);

  gemm_qkv<<<dim3(32, 8, 3), dim3(256), 0, stream>>>(
      xb, wqb, wkb, wvb, bq, bk, bv, qh, kh, vt);

  attn_kernel<<<dim3(1024), dim3(256), 0, stream>>>(qh, kh, vt, y);

  gemm_proj<<<dim3(32, 8), dim3(256), 0, stream>>>(y, wpb, bp, (float*)d_out);
}